// Round 7
// baseline (410.086 us; speedup 1.0000x reference)
//
#include <hip/hip_runtime.h>
#include <hip/hip_bf16.h>
#include <math.h>

typedef __hip_bfloat16 bf16;
typedef __attribute__((ext_vector_type(8))) short short8;
typedef __attribute__((ext_vector_type(4))) short short4v;
typedef __attribute__((ext_vector_type(4))) float f32x4;

#define SEQ 3072
#define HID 1152
#define NHEAD 16
#define HD 72
#define HDP 96
#define MLPD 4304
#define MLPP 4352

__device__ __forceinline__ void async_lds16(void* lds, const void* g) {
  __builtin_amdgcn_global_load_lds((const __attribute__((address_space(1))) void*)g,
                                   (__attribute__((address_space(3))) void*)lds,
                                   16, 0, 0);
}

__device__ __forceinline__ short bf16b(float x) {
  __hip_bfloat16 h = __float2bfloat16(x);
  return *reinterpret_cast<short*>(&h);
}

// one v_cvt_pk_bf16_f32: a -> low16, b -> high16 (RNE)
__device__ __forceinline__ unsigned cvt_pk2(float a, float b) {
  unsigned r;
  asm("v_cvt_pk_bf16_f32 %0, %1, %2" : "=v"(r) : "v"(a), "v"(b));
  return r;
}

// ---------------- weight cast kernels ----------------
__global__ __launch_bounds__(256) void cast_bf16_k(const float* __restrict__ in,
                                                   unsigned* __restrict__ out2, int n4) {
  int stride = gridDim.x * blockDim.x;
  for (int i = blockIdx.x * blockDim.x + threadIdx.x; i < n4; i += stride) {
    float4 u = ((const float4*)in)[i];
    uint2 w = make_uint2(cvt_pk2(u.x, u.y), cvt_pk2(u.z, u.w));
    ((uint2*)out2)[i] = w;
  }
}

// out [Rp][C] from in [R][C], rows >= R zero-filled
__global__ __launch_bounds__(256) void cast_pad_rows_k(const float* __restrict__ in,
                                                       unsigned* __restrict__ out2,
                                                       int R, int C4, int n4) {
  int stride = gridDim.x * blockDim.x;
  for (int i = blockIdx.x * blockDim.x + threadIdx.x; i < n4; i += stride) {
    int r = i / C4;
    uint2 w = make_uint2(0u, 0u);
    if (r < R) {
      float4 u = ((const float4*)in)[i];
      w = make_uint2(cvt_pk2(u.x, u.y), cvt_pk2(u.z, u.w));
    }
    ((uint2*)out2)[i] = w;
  }
}

// out [R][Cp] from in [R][C], cols >= C zero-filled
__global__ __launch_bounds__(256) void cast_pad_cols_k(const float* __restrict__ in,
                                                       unsigned* __restrict__ out2,
                                                       int C4, int Cp4, int n4) {
  int stride = gridDim.x * blockDim.x;
  for (int i = blockIdx.x * blockDim.x + threadIdx.x; i < n4; i += stride) {
    int r = i / Cp4, c4 = i - r * Cp4;
    uint2 w = make_uint2(0u, 0u);
    if (c4 < C4) {
      float4 u = ((const float4*)in)[r * C4 + c4];
      w = make_uint2(cvt_pk2(u.x, u.y), cvt_pk2(u.z, u.w));
    }
    ((uint2*)out2)[i] = w;
  }
}

// ---------------- layernorm (fp32 in -> bf16 out) ----------------
__global__ __launch_bounds__(256) void ln_k(const float* __restrict__ x,
                                            const float* __restrict__ g,
                                            const float* __restrict__ b,
                                            bf16* __restrict__ o) {
  int row = blockIdx.x;
  const float4* xr = (const float4*)(x + (size_t)row * HID);
  float sum = 0.f, sq = 0.f;
  for (int c = threadIdx.x; c < HID / 4; c += 256) {
    float4 u = xr[c];
    sum += u.x + u.y + u.z + u.w;
    sq += u.x * u.x + u.y * u.y + u.z * u.z + u.w * u.w;
  }
#pragma unroll
  for (int off = 32; off > 0; off >>= 1) {
    sum += __shfl_down(sum, off, 64);
    sq += __shfl_down(sq, off, 64);
  }
  __shared__ float red[8];
  int wv = threadIdx.x >> 6;
  if ((threadIdx.x & 63) == 0) { red[wv] = sum; red[4 + wv] = sq; }
  __syncthreads();
  if (threadIdx.x == 0) {
    red[0] = red[0] + red[1] + red[2] + red[3];
    red[4] = red[4] + red[5] + red[6] + red[7];
  }
  __syncthreads();
  float mu = red[0] * (1.f / HID);
  float var = red[4] * (1.f / HID) - mu * mu;
  float inv = rsqrtf(var + 1e-5f);
  uint2* o4 = (uint2*)(o + (size_t)row * HID);
  const float4* g4 = (const float4*)g;
  const float4* b4 = (const float4*)b;
  for (int c = threadIdx.x; c < HID / 4; c += 256) {
    float4 u = xr[c], gg = g4[c], bb = b4[c];
    uint2 w = make_uint2(cvt_pk2((u.x - mu) * inv * gg.x + bb.x, (u.y - mu) * inv * gg.y + bb.y),
                         cvt_pk2((u.z - mu) * inv * gg.z + bb.z, (u.w - mu) * inv * gg.w + bb.w));
    o4[c] = w;
  }
}

// ---------------- GEMM: C[M][N] = A[M][K] @ Bt[N][K]^T  (+ epilogue) ----------------
// 1-D grid, bijective XCD swizzle (x-major per XCD -> B-panel L2-resident).
// 4 LDS buffers, depth-3 prefetch, uniform vmcnt(8), wrapped tail stages.
// EPI 0: +bias -> fp32   1: +bias+res -> fp32   2: +bias, gelu -> bf16
template <int EPI>
__global__ __launch_bounds__(256) void gemm_bf16(const bf16* __restrict__ A,
                                                 const bf16* __restrict__ Bt,
                                                 const float* __restrict__ bias, int nbias,
                                                 const float* __restrict__ res,
                                                 float* __restrict__ outf,
                                                 bf16* __restrict__ outb,
                                                 int M, int N, int K) {
  __shared__ bf16 As[4][128 * 32];
  __shared__ bf16 Bs[4][128 * 32];
  const int t = threadIdx.x;
  const int l = t & 63;
  const int w = t >> 6;
  const int wr = w >> 1, wc = w & 1;
  const int lrow = l & 15;
  const int lk = (l >> 4) * 8;
  // XCD swizzle: each XCD owns a contiguous x-major range -> B-panel stays in its L2
  const int total = gridDim.x;
  const int wg = (blockIdx.x & 7) * (total >> 3) + (blockIdx.x >> 3);
  const int gyt = M >> 7;
  const int xt = wg / gyt;
  const int yt = wg - xt * gyt;
  const int m0 = yt * 128;
  const int n0 = xt * 128;
  const int arow = t >> 2;
  const int ach = (t & 3) * 8;

  const bf16* pa0 = &A[(size_t)(m0 + arow) * K + ach];
  const bf16* pa1 = &A[(size_t)(m0 + arow + 64) * K + ach];
  const bf16* pb0 = &Bt[(size_t)(n0 + arow) * K + ach];
  const bf16* pb1 = &Bt[(size_t)(n0 + arow + 64) * K + ach];
  auto STAGE = [&](int buf, int kt) {
    size_t off = (size_t)kt * 32;
    async_lds16(&As[buf][t * 8], pa0 + off);
    async_lds16(&As[buf][(256 + t) * 8], pa1 + off);
    async_lds16(&Bs[buf][t * 8], pb0 + off);
    async_lds16(&Bs[buf][(256 + t) * 8], pb1 + off);
  };

  f32x4 acc[4][4] = {};
  const int nkt = K >> 5;
  STAGE(0, 0);
  STAGE(1, 1);
  STAGE(2, 2);
  for (int kt = 0; kt < nkt; ++kt) {
    asm volatile("s_waitcnt vmcnt(8)" ::: "memory");  // stage kt landed; kt+1,kt+2 in flight
    __builtin_amdgcn_s_barrier();
    int ks = kt + 3;
    if (ks >= nkt) ks -= nkt;  // wrapped: tail stages land in never-read buffers
    STAGE((kt + 3) & 3, ks);

    const int bcur = kt & 3;
    short8 af[4], bfr[4];
#pragma unroll
    for (int i = 0; i < 4; ++i)
      af[i] = *(const short8*)&As[bcur][(wr * 64 + i * 16 + lrow) * 32 + lk];
#pragma unroll
    for (int i = 0; i < 4; ++i)
      bfr[i] = *(const short8*)&Bs[bcur][(wc * 64 + i * 16 + lrow) * 32 + lk];
    __builtin_amdgcn_s_setprio(1);
#pragma unroll
    for (int i = 0; i < 4; ++i)
#pragma unroll
      for (int j = 0; j < 4; ++j)
        acc[i][j] = __builtin_amdgcn_mfma_f32_16x16x32_bf16(af[i], bfr[j], acc[i][j], 0, 0, 0);
    __builtin_amdgcn_s_setprio(0);
  }
  asm volatile("s_waitcnt vmcnt(0)" ::: "memory");  // drain stale wrapped stages before exit

#pragma unroll
  for (int i = 0; i < 4; ++i) {
    int rowb = m0 + wr * 64 + i * 16 + (l >> 4) * 4;
#pragma unroll
    for (int j = 0; j < 4; ++j) {
      int col = n0 + wc * 64 + j * 16 + lrow;
      float bv = (col < nbias) ? bias[col] : 0.f;
#pragma unroll
      for (int r2 = 0; r2 < 4; ++r2) {
        size_t idx = (size_t)(rowb + r2) * N + col;
        float v = acc[i][j][r2] + bv;
        if (EPI == 0) {
          outf[idx] = v;
        } else if (EPI == 1) {
          outf[idx] = v + res[idx];
        } else {
          float u = 0.7978845608028654f * (v + 0.044715f * v * v * v);
          u = fminf(fmaxf(u, -15.f), 15.f);
          float tt = __expf(2.f * u);
          outb[idx] = __float2bfloat16(v * tt / (tt + 1.f));
        }
      }
    }
  }
}

// ---------------- rope + qkv split ----------------
__global__ __launch_bounds__(256) void rope_split(const float* __restrict__ xqkv,
                                                  const float* __restrict__ cosb,
                                                  const float* __restrict__ sinb,
                                                  bf16* __restrict__ qp,
                                                  bf16* __restrict__ kp,
                                                  bf16* __restrict__ vt) {
  __shared__ bf16 vl[64][72];
  const int t = threadIdx.x;
  const int h = blockIdx.y;
  const int s0 = blockIdx.x * 64;
  const float scale = 0.11785113019775793f;  // 1/sqrt(72)
  for (int idx = t; idx < 64 * 48; idx += 256) {
    int sl = idx / 48, pi = idx - sl * 48;
    int srow = s0 + sl;
    size_t obase = ((size_t)h * SEQ + srow) * HDP + 2 * pi;
    if (pi < 36) {
      const float* xr = xqkv + (size_t)srow * (3 * HID) + h * HD + 2 * pi;
      float qr = xr[0], qi = xr[1];
      float kr = xr[HID], ki = xr[HID + 1];
      float c = cosb[srow * 36 + pi], sn = sinb[srow * 36 + pi];
      *(unsigned*)&qp[obase] = cvt_pk2((qr * c - qi * sn) * scale, (qr * sn + qi * c) * scale);
      *(unsigned*)&kp[obase] = cvt_pk2(kr * c - ki * sn, kr * sn + ki * c);
    } else {
      *(unsigned*)&qp[obase] = 0u;
      *(unsigned*)&kp[obase] = 0u;
    }
  }
  for (int idx = t; idx < 64 * 72; idx += 256) {
    int sl = idx / 72, d = idx - sl * 72;
    vl[sl][d] = __float2bfloat16(xqkv[(size_t)(s0 + sl) * (3 * HID) + 2 * HID + h * HD + d]);
  }
  __syncthreads();
  bf16 z = __float2bfloat16(0.f);
  for (int idx = t; idx < HDP * 64; idx += 256) {
    int d = idx / 64, sl = idx - d * 64;
    vt[((size_t)h * HDP + d) * SEQ + s0 + sl] = (d < 72) ? vl[sl][d] : z;
  }
}

// ---------------- flash attention (fully swapped, pipelined, triple-buffered) ----------------
__global__ __launch_bounds__(256) void flash_attn(const bf16* __restrict__ q,
                                                  const bf16* __restrict__ kk,
                                                  const bf16* __restrict__ vT,
                                                  bf16* __restrict__ o) {
  __shared__ alignas(16) bf16 KV3[3 * 6144];
  __shared__ alignas(16) bf16 Pl[4][512];
  const int t = threadIdx.x;
  const int l = t & 63;
  const int w = t >> 6;
  const int g = l >> 4;
  const int lrow = l & 15;
  const int bid = blockIdx.x;
  const int kq = bid >> 3;
  const int h = (bid & 7) * 2 + (kq & 1);
  const int q0 = (kq >> 1) * 64 + w * 16;
  const int NT = SEQ / 32;

  const bf16* sbase[3];
  int smul[3];
#pragma unroll
  for (int i = 0; i < 3; ++i) {
    int s = t + i * 256;
    if (s < 384) {
      int cb = s >> 5, kv = s & 31;
      sbase[i] = kk + ((size_t)h * SEQ + kv) * HDP + cb * 8;
      smul[i] = 32 * HDP;
    } else {
      int vs = s - 384;
      int cb = vs / 96, d = vs - cb * 96;
      sbase[i] = vT + ((size_t)h * HDP + d) * SEQ + cb * 8;
      smul[i] = 32;
    }
  }
  auto STAGE = [&](int tile, int bufOff) {
#pragma unroll
    for (int i = 0; i < 3; ++i)
      async_lds16(&KV3[bufOff + (t + i * 256) * 8], sbase[i] + (size_t)tile * smul[i]);
  };

  short8 qf[3];
#pragma unroll
  for (int f = 0; f < 3; ++f)
    qf[f] = *(const short8*)&q[((size_t)h * SEQ + q0 + lrow) * HDP + f * 32 + g * 8];

  float m_r = -1e30f, l_r = 0.f;
  f32x4 oa[5] = {};

  STAGE(0, 0);
  STAGE(1, 6144);
  STAGE(2, 12288);
  asm volatile("s_waitcnt vmcnt(6)" ::: "memory");
  __builtin_amdgcn_s_barrier();

  f32x4 stA[2] = {}, stB[2];
  int b0 = 0;
#pragma unroll
  for (int nf = 0; nf < 2; ++nf)
#pragma unroll
    for (int f = 0; f < 3; ++f) {
      short8 kfrag = *(const short8*)&KV3[0 + (f * 4 + g) * 256 + (nf * 16 + lrow) * 8];
      stA[nf] = __builtin_amdgcn_mfma_f32_16x16x32_bf16(kfrag, qf[f], stA[nf], 0, 0, 0);
    }

  for (int kt = 0; kt < NT - 1; ++kt) {
    int b1 = b0 + 6144;
    if (b1 == 18432) b1 = 0;
    asm volatile("s_waitcnt vmcnt(3)" ::: "memory");
    __builtin_amdgcn_s_barrier();

    stB[0] = (f32x4){0.f, 0.f, 0.f, 0.f};
    stB[1] = (f32x4){0.f, 0.f, 0.f, 0.f};
    __builtin_amdgcn_s_setprio(1);
#pragma unroll
    for (int nf = 0; nf < 2; ++nf)
#pragma unroll
      for (int f = 0; f < 3; ++f) {
        short8 kfrag = *(const short8*)&KV3[b1 + (f * 4 + g) * 256 + (nf * 16 + lrow) * 8];
        stB[nf] = __builtin_amdgcn_mfma_f32_16x16x32_bf16(kfrag, qf[f], stB[nf], 0, 0, 0);
      }
    __builtin_amdgcn_s_setprio(0);

    float pmax = fmaxf(fmaxf(fmaxf(stA[0][0], stA[0][1]), fmaxf(stA[0][2], stA[0][3])),
                       fmaxf(fmaxf(stA[1][0], stA[1][1]), fmaxf(stA[1][2], stA[1][3])));
    if (!__all(pmax - m_r <= 8.f)) {
      float rm = pmax;
      rm = fmaxf(rm, __shfl_xor(rm, 16, 64));
      rm = fmaxf(rm, __shfl_xor(rm, 32, 64));
      float mn = fmaxf(m_r, rm);
      float alpha = __expf(m_r - mn);
      l_r *= alpha;
#pragma unroll
      for (int nf = 0; nf < 5; ++nf)
#pragma unroll
        for (int r = 0; r < 4; ++r) oa[nf][r] *= alpha;
      m_r = mn;
    }
#pragma unroll
    for (int nf = 0; nf < 2; ++nf)
#pragma unroll
      for (int r = 0; r < 4; ++r) stA[nf][r] = __expf(stA[nf][r] - m_r);
    l_r += (stA[0][0] + stA[0][1]) + (stA[0][2] + stA[0][3]) +
           (stA[1][0] + stA[1][1]) + (stA[1][2] + stA[1][3]);

#pragma unroll
    for (int nf = 0; nf < 2; ++nf) {
      uint2* dst = (uint2*)&Pl[w][(2 * nf + (g >> 1)) * 128 + lrow * 8 + (g & 1) * 4];
      *dst = make_uint2(cvt_pk2(stA[nf][0], stA[nf][1]), cvt_pk2(stA[nf][2], stA[nf][3]));
    }

    {
      short8 pa = *(const short8*)&Pl[w][g * 128 + lrow * 8];
      __builtin_amdgcn_s_setprio(1);
#pragma unroll
      for (int nf = 0; nf < 5; ++nf) {
        short8 bv = *(const short8*)&KV3[b0 + 3072 + g * 768 + (nf * 16 + lrow) * 8];
        oa[nf] = __builtin_amdgcn_mfma_f32_16x16x32_bf16(bv, pa, oa[nf], 0, 0, 0);
      }
      __builtin_amdgcn_s_setprio(0);
    }

    asm volatile("s_waitcnt lgkmcnt(0)" ::: "memory");
    __builtin_amdgcn_s_barrier();
    int s = kt + 3;
    if (s >= NT) s -= NT;
    STAGE(s, b0);
    stA[0] = stB[0];
    stA[1] = stB[1];
    b0 = b1;
  }

  {
    float pmax = fmaxf(fmaxf(fmaxf(stA[0][0], stA[0][1]), fmaxf(stA[0][2], stA[0][3])),
                       fmaxf(fmaxf(stA[1][0], stA[1][1]), fmaxf(stA[1][2], stA[1][3])));
    if (!__all(pmax - m_r <= 8.f)) {
      float rm = pmax;
      rm = fmaxf(rm, __shfl_xor(rm, 16, 64));
      rm = fmaxf(rm, __shfl_xor(rm, 32, 64));
      float mn = fmaxf(m_r, rm);
      float alpha = __expf(m_r - mn);
      l_r *= alpha;
#pragma unroll
      for (int nf = 0; nf < 5; ++nf)
#pragma unroll
        for (int r = 0; r < 4; ++r) oa[nf][r] *= alpha;
      m_r = mn;
    }
#pragma unroll
    for (int nf = 0; nf < 2; ++nf)
#pragma unroll
      for (int r = 0; r < 4; ++r) stA[nf][r] = __expf(stA[nf][r] - m_r);
    l_r += (stA[0][0] + stA[0][1]) + (stA[0][2] + stA[0][3]) +
           (stA[1][0] + stA[1][1]) + (stA[1][2] + stA[1][3]);
#pragma unroll
    for (int nf = 0; nf < 2; ++nf) {
      uint2* dst = (uint2*)&Pl[w][(2 * nf + (g >> 1)) * 128 + lrow * 8 + (g & 1) * 4];
      *dst = make_uint2(cvt_pk2(stA[nf][0], stA[nf][1]), cvt_pk2(stA[nf][2], stA[nf][3]));
    }
    short8 pa = *(const short8*)&Pl[w][g * 128 + lrow * 8];
#pragma unroll
    for (int nf = 0; nf < 5; ++nf) {
      short8 bv = *(const short8*)&KV3[b0 + 3072 + g * 768 + (nf * 16 + lrow) * 8];
      oa[nf] = __builtin_amdgcn_mfma_f32_16x16x32_bf16(bv, pa, oa[nf], 0, 0, 0);
    }
  }

  float lt = l_r;
  lt += __shfl_xor(lt, 16, 64);
  lt += __shfl_xor(lt, 32, 64);
  float rcp = 1.f / lt;
  size_t obase = (size_t)(q0 + lrow) * HID + h * HD;
#pragma unroll
  for (int nf = 0; nf < 5; ++nf) {
    int d = nf * 16 + g * 4;
    if (d + 3 < HD) {
      uint2 pk = make_uint2(cvt_pk2(oa[nf][0] * rcp, oa[nf][1] * rcp),
                            cvt_pk2(oa[nf][2] * rcp, oa[nf][3] * rcp));
      *(uint2*)&o[obase + d] = pk;
    }
  }
}

// ---------------- launch ----------------
extern "C" void kernel_launch(void* const* d_in, const int* in_sizes, int n_in,
                              void* d_out, int out_size, void* d_ws, size_t ws_size,
                              hipStream_t stream) {
  (void)in_sizes; (void)n_in; (void)out_size;
  const float* hidden = (const float*)d_in[0];
  const float* cosb = (const float*)d_in[1];
  const float* sinb = (const float*)d_in[2];
  const float* ln0g = (const float*)d_in[3];
  const float* ln0b = (const float*)d_in[4];
  const float* ln1g = (const float*)d_in[5];
  const float* ln1b = (const float*)d_in[6];
  const float* wqkv = (const float*)d_in[7];
  const float* bqkv = (const float*)d_in[8];
  const float* wo = (const float*)d_in[9];
  const float* bo = (const float*)d_in[10];
  const float* w0 = (const float*)d_in[11];
  const float* b0 = (const float*)d_in[12];
  const float* w1 = (const float*)d_in[13];
  const float* b1 = (const float*)d_in[14];

  char* p = (char*)d_ws;
  auto alloc = [&](size_t n) {
    char* r = p;
    p += (n + 255) & ~(size_t)255;
    return r;
  };
  bf16* wqkv_bf = (bf16*)alloc((size_t)3 * HID * HID * 2);
  bf16* wo_bf = (bf16*)alloc((size_t)HID * HID * 2);
  bf16* fc0_bf = (bf16*)alloc((size_t)MLPP * HID * 2);
  bf16* fc1_bf = (bf16*)alloc((size_t)HID * MLPP * 2);
  bf16* ln0_bf = (bf16*)alloc((size_t)SEQ * HID * 2);
  float* xqkv = (float*)alloc((size_t)SEQ * 3 * HID * 4);
  bf16* qp = (bf16*)alloc((size_t)NHEAD * SEQ * HDP * 2);
  bf16* kp = (bf16*)alloc((size_t)NHEAD * SEQ * HDP * 2);
  bf16* vt = (bf16*)alloc((size_t)NHEAD * HDP * SEQ * 2);
  bf16* attn_bf = (bf16*)alloc((size_t)SEQ * HID * 2);
  float* h1 = (float*)alloc((size_t)SEQ * HID * 4);
  bf16* ln1_bf = (bf16*)alloc((size_t)SEQ * HID * 2);
  bf16* gelu_bf = (bf16*)alloc((size_t)SEQ * MLPP * 2);
  if ((size_t)(p - (char*)d_ws) > ws_size) return;

  dim3 blk(256);
  cast_bf16_k<<<2048, blk, 0, stream>>>(wqkv, (unsigned*)wqkv_bf, 3 * HID * HID / 4);
  cast_bf16_k<<<1024, blk, 0, stream>>>(wo, (unsigned*)wo_bf, HID * HID / 4);
  cast_pad_rows_k<<<2048, blk, 0, stream>>>(w0, (unsigned*)fc0_bf, MLPD, HID / 4, MLPP * HID / 4);
  cast_pad_cols_k<<<2048, blk, 0, stream>>>(w1, (unsigned*)fc1_bf, MLPD / 4, MLPP / 4, HID * MLPP / 4);
  ln_k<<<SEQ, blk, 0, stream>>>(hidden, ln0g, ln0b, ln0_bf);
  gemm_bf16<0><<<dim3((3 * HID / 128) * (SEQ / 128)), blk, 0, stream>>>(
      ln0_bf, wqkv_bf, bqkv, 3 * HID, nullptr, xqkv, nullptr, SEQ, 3 * HID, HID);
  rope_split<<<dim3(SEQ / 64, NHEAD), blk, 0, stream>>>(xqkv, cosb, sinb, qp, kp, vt);
  flash_attn<<<dim3(768), blk, 0, stream>>>(qp, kp, vt, attn_bf);
  gemm_bf16<1><<<dim3((HID / 128) * (SEQ / 128)), blk, 0, stream>>>(
      attn_bf, wo_bf, bo, HID, hidden, h1, nullptr, SEQ, HID, HID);
  ln_k<<<SEQ, blk, 0, stream>>>(h1, ln1g, ln1b, ln1_bf);
  gemm_bf16<2><<<dim3((MLPP / 128) * (SEQ / 128)), blk, 0, stream>>>(
      ln1_bf, fc0_bf, b0, MLPD, nullptr, nullptr, gelu_bf, SEQ, MLPP, HID);
  gemm_bf16<1><<<dim3((HID / 128) * (SEQ / 128)), blk, 0, stream>>>(
      gelu_bf, fc1_bf, b1, HID, h1, (float*)d_out, nullptr, SEQ, HID, MLPP);
}

// Round 8
// 399.919 us; speedup vs baseline: 1.0254x; 1.0254x over previous
//
#include <hip/hip_runtime.h>
#include <hip/hip_bf16.h>
#include <math.h>

typedef __hip_bfloat16 bf16;
typedef __attribute__((ext_vector_type(8))) short short8;
typedef __attribute__((ext_vector_type(4))) short short4v;
typedef __attribute__((ext_vector_type(4))) float f32x4;

#define SEQ 3072
#define HID 1152
#define NHEAD 16
#define HD 72
#define HDP 96
#define MLPD 4304
#define MLPP 4352

__device__ __forceinline__ void async_lds16(void* lds, const void* g) {
  __builtin_amdgcn_global_load_lds((const __attribute__((address_space(1))) void*)g,
                                   (__attribute__((address_space(3))) void*)lds,
                                   16, 0, 0);
}

// one v_cvt_pk_bf16_f32: a -> low16, b -> high16 (RNE)
__device__ __forceinline__ unsigned cvt_pk2(float a, float b) {
  unsigned r;
  asm("v_cvt_pk_bf16_f32 %0, %1, %2" : "=v"(r) : "v"(a), "v"(b));
  return r;
}

// raw v_exp_f32: 2^x
__device__ __forceinline__ float exp2a(float x) {
  float r;
  asm("v_exp_f32 %0, %1" : "=v"(r) : "v"(x));
  return r;
}

// ---------------- weight cast kernels ----------------
__global__ __launch_bounds__(256) void cast_bf16_k(const float* __restrict__ in,
                                                   unsigned* __restrict__ out2, int n4) {
  int stride = gridDim.x * blockDim.x;
  for (int i = blockIdx.x * blockDim.x + threadIdx.x; i < n4; i += stride) {
    float4 u = ((const float4*)in)[i];
    uint2 w = make_uint2(cvt_pk2(u.x, u.y), cvt_pk2(u.z, u.w));
    ((uint2*)out2)[i] = w;
  }
}

__global__ __launch_bounds__(256) void cast_pad_rows_k(const float* __restrict__ in,
                                                       unsigned* __restrict__ out2,
                                                       int R, int C4, int n4) {
  int stride = gridDim.x * blockDim.x;
  for (int i = blockIdx.x * blockDim.x + threadIdx.x; i < n4; i += stride) {
    int r = i / C4;
    uint2 w = make_uint2(0u, 0u);
    if (r < R) {
      float4 u = ((const float4*)in)[i];
      w = make_uint2(cvt_pk2(u.x, u.y), cvt_pk2(u.z, u.w));
    }
    ((uint2*)out2)[i] = w;
  }
}

__global__ __launch_bounds__(256) void cast_pad_cols_k(const float* __restrict__ in,
                                                       unsigned* __restrict__ out2,
                                                       int C4, int Cp4, int n4) {
  int stride = gridDim.x * blockDim.x;
  for (int i = blockIdx.x * blockDim.x + threadIdx.x; i < n4; i += stride) {
    int r = i / Cp4, c4 = i - r * Cp4;
    uint2 w = make_uint2(0u, 0u);
    if (c4 < C4) {
      float4 u = ((const float4*)in)[r * C4 + c4];
      w = make_uint2(cvt_pk2(u.x, u.y), cvt_pk2(u.z, u.w));
    }
    ((uint2*)out2)[i] = w;
  }
}

// ---------------- layernorm (fp32 in -> bf16 out) ----------------
__global__ __launch_bounds__(256) void ln_k(const float* __restrict__ x,
                                            const float* __restrict__ g,
                                            const float* __restrict__ b,
                                            bf16* __restrict__ o) {
  int row = blockIdx.x;
  const float4* xr = (const float4*)(x + (size_t)row * HID);
  float sum = 0.f, sq = 0.f;
  for (int c = threadIdx.x; c < HID / 4; c += 256) {
    float4 u = xr[c];
    sum += u.x + u.y + u.z + u.w;
    sq += u.x * u.x + u.y * u.y + u.z * u.z + u.w * u.w;
  }
#pragma unroll
  for (int off = 32; off > 0; off >>= 1) {
    sum += __shfl_down(sum, off, 64);
    sq += __shfl_down(sq, off, 64);
  }
  __shared__ float red[8];
  int wv = threadIdx.x >> 6;
  if ((threadIdx.x & 63) == 0) { red[wv] = sum; red[4 + wv] = sq; }
  __syncthreads();
  if (threadIdx.x == 0) {
    red[0] = red[0] + red[1] + red[2] + red[3];
    red[4] = red[4] + red[5] + red[6] + red[7];
  }
  __syncthreads();
  float mu = red[0] * (1.f / HID);
  float var = red[4] * (1.f / HID) - mu * mu;
  float inv = rsqrtf(var + 1e-5f);
  uint2* o4 = (uint2*)(o + (size_t)row * HID);
  const float4* g4 = (const float4*)g;
  const float4* b4 = (const float4*)b;
  for (int c = threadIdx.x; c < HID / 4; c += 256) {
    float4 u = xr[c], gg = g4[c], bb = b4[c];
    uint2 w = make_uint2(cvt_pk2((u.x - mu) * inv * gg.x + bb.x, (u.y - mu) * inv * gg.y + bb.y),
                         cvt_pk2((u.z - mu) * inv * gg.z + bb.z, (u.w - mu) * inv * gg.w + bb.w));
    o4[c] = w;
  }
}

// ---------------- GEMM: C[M][N] = A[M][K] @ Bt[N][K]^T  (+ epilogue) ----------------
// 3 LDS buffers (48KB -> 3 blocks/CU), depth-2 prefetch, counted vmcnt,
// bijective XCD swizzle (x-major per XCD -> B-panel L2-resident).
// EPI 0: +bias -> fp32   1: +bias+res -> fp32   2: +bias, gelu -> bf16
template <int EPI>
__global__ __launch_bounds__(256) void gemm_bf16(const bf16* __restrict__ A,
                                                 const bf16* __restrict__ Bt,
                                                 const float* __restrict__ bias, int nbias,
                                                 const float* __restrict__ res,
                                                 float* __restrict__ outf,
                                                 bf16* __restrict__ outb,
                                                 int M, int N, int K) {
  __shared__ bf16 As[3][128 * 32];
  __shared__ bf16 Bs[3][128 * 32];
  const int t = threadIdx.x;
  const int l = t & 63;
  const int w = t >> 6;
  const int wr = w >> 1, wc = w & 1;
  const int lrow = l & 15;
  const int lk = (l >> 4) * 8;
  const int wg = (blockIdx.x & 7) * (gridDim.x >> 3) + (blockIdx.x >> 3);
  const int gyt = M >> 7;
  const int xt = wg / gyt;
  const int yt = wg - xt * gyt;
  const int m0 = yt * 128;
  const int n0 = xt * 128;
  const int arow = t >> 2;
  const int ach = (t & 3) * 8;

  const bf16* pa0 = &A[(size_t)(m0 + arow) * K + ach];
  const bf16* pa1 = &A[(size_t)(m0 + arow + 64) * K + ach];
  const bf16* pb0 = &Bt[(size_t)(n0 + arow) * K + ach];
  const bf16* pb1 = &Bt[(size_t)(n0 + arow + 64) * K + ach];
  auto STAGE = [&](int buf, int kt) {
    size_t off = (size_t)kt * 32;
    async_lds16(&As[buf][t * 8], pa0 + off);
    async_lds16(&As[buf][(256 + t) * 8], pa1 + off);
    async_lds16(&Bs[buf][t * 8], pb0 + off);
    async_lds16(&Bs[buf][(256 + t) * 8], pb1 + off);
  };

  f32x4 acc[4][4] = {};
  const int nkt = K >> 5;
  STAGE(0, 0);
  STAGE(1, 1);
  int bcur = 0;
  for (int kt = 0; kt < nkt; ++kt) {
    if (kt + 1 < nkt) {
      asm volatile("s_waitcnt vmcnt(4)" ::: "memory");  // stage kt landed; kt+1 in flight
    } else {
      asm volatile("s_waitcnt vmcnt(0)" ::: "memory");
    }
    __builtin_amdgcn_s_barrier();
    int bn2 = bcur + 2;
    if (bn2 >= 3) bn2 -= 3;
    if (kt + 2 < nkt) STAGE(bn2, kt + 2);

    short8 af[4], bfr[4];
#pragma unroll
    for (int i = 0; i < 4; ++i)
      af[i] = *(const short8*)&As[bcur][(wr * 64 + i * 16 + lrow) * 32 + lk];
#pragma unroll
    for (int i = 0; i < 4; ++i)
      bfr[i] = *(const short8*)&Bs[bcur][(wc * 64 + i * 16 + lrow) * 32 + lk];
    __builtin_amdgcn_s_setprio(1);
#pragma unroll
    for (int i = 0; i < 4; ++i)
#pragma unroll
      for (int j = 0; j < 4; ++j)
        acc[i][j] = __builtin_amdgcn_mfma_f32_16x16x32_bf16(af[i], bfr[j], acc[i][j], 0, 0, 0);
    __builtin_amdgcn_s_setprio(0);
    ++bcur;
    if (bcur == 3) bcur = 0;
  }

#pragma unroll
  for (int i = 0; i < 4; ++i) {
    int rowb = m0 + wr * 64 + i * 16 + (l >> 4) * 4;
#pragma unroll
    for (int j = 0; j < 4; ++j) {
      int col = n0 + wc * 64 + j * 16 + lrow;
      float bv = (col < nbias) ? bias[col] : 0.f;
#pragma unroll
      for (int r2 = 0; r2 < 4; ++r2) {
        size_t idx = (size_t)(rowb + r2) * N + col;
        float v = acc[i][j][r2] + bv;
        if (EPI == 0) {
          outf[idx] = v;
        } else if (EPI == 1) {
          outf[idx] = v + res[idx];
        } else {
          float u = 0.7978845608028654f * (v + 0.044715f * v * v * v);
          u = fminf(fmaxf(u, -15.f), 15.f);
          float tt = __expf(2.f * u);
          outb[idx] = __float2bfloat16(v * tt / (tt + 1.f));
        }
      }
    }
  }
}

// ---------------- rope + qkv split ----------------
// q scale folds log2(e) so flash softmax runs in exp2 domain.
__global__ __launch_bounds__(256) void rope_split(const float* __restrict__ xqkv,
                                                  const float* __restrict__ cosb,
                                                  const float* __restrict__ sinb,
                                                  bf16* __restrict__ qp,
                                                  bf16* __restrict__ kp,
                                                  bf16* __restrict__ vt) {
  __shared__ bf16 vl[64][72];
  const int t = threadIdx.x;
  const int h = blockIdx.y;
  const int s0 = blockIdx.x * 64;
  const float scale = 0.17002445f;  // (1/sqrt(72)) * log2(e)
  for (int idx = t; idx < 64 * 48; idx += 256) {
    int sl = idx / 48, pi = idx - sl * 48;
    int srow = s0 + sl;
    size_t obase = ((size_t)h * SEQ + srow) * HDP + 2 * pi;
    if (pi < 36) {
      const float* xr = xqkv + (size_t)srow * (3 * HID) + h * HD + 2 * pi;
      float qr = xr[0], qi = xr[1];
      float kr = xr[HID], ki = xr[HID + 1];
      float c = cosb[srow * 36 + pi], sn = sinb[srow * 36 + pi];
      *(unsigned*)&qp[obase] = cvt_pk2((qr * c - qi * sn) * scale, (qr * sn + qi * c) * scale);
      *(unsigned*)&kp[obase] = cvt_pk2(kr * c - ki * sn, kr * sn + ki * c);
    } else {
      *(unsigned*)&qp[obase] = 0u;
      *(unsigned*)&kp[obase] = 0u;
    }
  }
  for (int idx = t; idx < 64 * 72; idx += 256) {
    int sl = idx / 72, d = idx - sl * 72;
    vl[sl][d] = __float2bfloat16(xqkv[(size_t)(s0 + sl) * (3 * HID) + 2 * HID + h * HD + d]);
  }
  __syncthreads();
  bf16 z = __float2bfloat16(0.f);
  for (int idx = t; idx < HDP * 64; idx += 256) {
    int d = idx / 64, sl = idx - d * 64;
    vt[((size_t)h * HDP + d) * SEQ + s0 + sl] = (d < 72) ? vl[sl][d] : z;
  }
}

// ---------------- flash attention ----------------
// 2-wave blocks (128 thr), 32 q-rows per wave in TWO 16-row sets sharing all
// K/V LDS reads. Swapped operands throughout (lane-local softmax), exp2-domain
// (log2e folded into q), defer-max THR = 8*log2e = 11.54, triple-buffered KV.
__global__ __launch_bounds__(128) void flash_attn(const bf16* __restrict__ q,
                                                  const bf16* __restrict__ kk,
                                                  const bf16* __restrict__ vT,
                                                  bf16* __restrict__ o) {
  __shared__ alignas(16) bf16 KV3[3 * 6144];
  __shared__ alignas(16) bf16 Pl[2][2][512];
  const int t = threadIdx.x;
  const int l = t & 63;
  const int w = t >> 6;  // 0..1
  const int g = l >> 4;
  const int lrow = l & 15;
  const int bid = blockIdx.x;
  const int kq = bid >> 3;
  const int h = (bid & 7) * 2 + (kq & 1);
  const int q0 = (kq >> 1) * 64 + w * 32;
  const int NT = SEQ / 32;

  const bf16* sbase[6];
  int smul[6];
#pragma unroll
  for (int i = 0; i < 6; ++i) {
    int s = t + i * 128;
    if (s < 384) {
      int cb = s >> 5, kv = s & 31;
      sbase[i] = kk + ((size_t)h * SEQ + kv) * HDP + cb * 8;
      smul[i] = 32 * HDP;
    } else {
      int vs = s - 384;
      int cb = vs / 96, d = vs - cb * 96;
      sbase[i] = vT + ((size_t)h * HDP + d) * SEQ + cb * 8;
      smul[i] = 32;
    }
  }
  auto STAGE = [&](int tile, int bufOff) {
#pragma unroll
    for (int i = 0; i < 6; ++i)
      async_lds16(&KV3[bufOff + (t + i * 128) * 8], sbase[i] + (size_t)tile * smul[i]);
  };

  short8 qf[2][3];
#pragma unroll
  for (int ss = 0; ss < 2; ++ss)
#pragma unroll
    for (int f = 0; f < 3; ++f)
      qf[ss][f] =
          *(const short8*)&q[((size_t)h * SEQ + q0 + ss * 16 + lrow) * HDP + f * 32 + g * 8];

  float m_r[2] = {-1e30f, -1e30f};
  float l_r[2] = {0.f, 0.f};
  f32x4 oa0[5] = {}, oa1[5] = {};

  STAGE(0, 0);
  STAGE(1, 6144);
  STAGE(2, 12288);
  asm volatile("s_waitcnt vmcnt(12)" ::: "memory");
  __builtin_amdgcn_s_barrier();

  f32x4 stA[2][2] = {}, stB[2][2];
  int b0 = 0;
#pragma unroll
  for (int nf = 0; nf < 2; ++nf)
#pragma unroll
    for (int f = 0; f < 3; ++f) {
      short8 kfrag = *(const short8*)&KV3[0 + (f * 4 + g) * 256 + (nf * 16 + lrow) * 8];
      stA[0][nf] = __builtin_amdgcn_mfma_f32_16x16x32_bf16(kfrag, qf[0][f], stA[0][nf], 0, 0, 0);
      stA[1][nf] = __builtin_amdgcn_mfma_f32_16x16x32_bf16(kfrag, qf[1][f], stA[1][nf], 0, 0, 0);
    }

  // softmax for one set: defer-max (exp2 domain), P-write into Pl[w][ss]
  auto SOFTMAX = [&](f32x4* st, float& mr, float& lr, f32x4* oav, int ss) {
    float pmax = fmaxf(fmaxf(fmaxf(st[0][0], st[0][1]), fmaxf(st[0][2], st[0][3])),
                       fmaxf(fmaxf(st[1][0], st[1][1]), fmaxf(st[1][2], st[1][3])));
    if (!__all(pmax - mr <= 11.54f)) {
      float rm = pmax;
      rm = fmaxf(rm, __shfl_xor(rm, 16, 64));
      rm = fmaxf(rm, __shfl_xor(rm, 32, 64));
      float mn = fmaxf(mr, rm);
      float alpha = exp2a(mr - mn);
      lr *= alpha;
#pragma unroll
      for (int nf = 0; nf < 5; ++nf)
#pragma unroll
        for (int r = 0; r < 4; ++r) oav[nf][r] *= alpha;
      mr = mn;
    }
#pragma unroll
    for (int nf = 0; nf < 2; ++nf)
#pragma unroll
      for (int r = 0; r < 4; ++r) st[nf][r] = exp2a(st[nf][r] - mr);
    lr += (st[0][0] + st[0][1]) + (st[0][2] + st[0][3]) +
          (st[1][0] + st[1][1]) + (st[1][2] + st[1][3]);
#pragma unroll
    for (int nf = 0; nf < 2; ++nf) {
      uint2* dst = (uint2*)&Pl[w][ss][(2 * nf + (g >> 1)) * 128 + lrow * 8 + (g & 1) * 4];
      *dst = make_uint2(cvt_pk2(st[nf][0], st[nf][1]), cvt_pk2(st[nf][2], st[nf][3]));
    }
  };

  for (int kt = 0; kt < NT - 1; ++kt) {
    int b1 = b0 + 6144;
    if (b1 == 18432) b1 = 0;
    asm volatile("s_waitcnt vmcnt(6)" ::: "memory");
    __builtin_amdgcn_s_barrier();

    // QK(kt+1) from b1, both sets share kfrag
#pragma unroll
    for (int s2 = 0; s2 < 2; ++s2)
#pragma unroll
      for (int nf = 0; nf < 2; ++nf) stB[s2][nf] = (f32x4){0.f, 0.f, 0.f, 0.f};
    __builtin_amdgcn_s_setprio(1);
#pragma unroll
    for (int nf = 0; nf < 2; ++nf)
#pragma unroll
      for (int f = 0; f < 3; ++f) {
        short8 kfrag = *(const short8*)&KV3[b1 + (f * 4 + g) * 256 + (nf * 16 + lrow) * 8];
        stB[0][nf] = __builtin_amdgcn_mfma_f32_16x16x32_bf16(kfrag, qf[0][f], stB[0][nf], 0, 0, 0);
        stB[1][nf] = __builtin_amdgcn_mfma_f32_16x16x32_bf16(kfrag, qf[1][f], stB[1][nf], 0, 0, 0);
      }
    __builtin_amdgcn_s_setprio(0);

    SOFTMAX(stA[0], m_r[0], l_r[0], oa0, 0);
    SOFTMAX(stA[1], m_r[1], l_r[1], oa1, 1);

    // PV(kt) from b0: V frag shared by both sets
    {
      short8 pa0 = *(const short8*)&Pl[w][0][g * 128 + lrow * 8];
      short8 pa1 = *(const short8*)&Pl[w][1][g * 128 + lrow * 8];
      __builtin_amdgcn_s_setprio(1);
#pragma unroll
      for (int nf = 0; nf < 5; ++nf) {
        short8 bv = *(const short8*)&KV3[b0 + 3072 + g * 768 + (nf * 16 + lrow) * 8];
        oa0[nf] = __builtin_amdgcn_mfma_f32_16x16x32_bf16(bv, pa0, oa0[nf], 0, 0, 0);
        oa1[nf] = __builtin_amdgcn_mfma_f32_16x16x32_bf16(bv, pa1, oa1[nf], 0, 0, 0);
      }
      __builtin_amdgcn_s_setprio(0);
    }

    asm volatile("s_waitcnt lgkmcnt(0)" ::: "memory");
    __builtin_amdgcn_s_barrier();
    int s = kt + 3;
    if (s >= NT) s -= NT;
    STAGE(s, b0);
#pragma unroll
    for (int s2 = 0; s2 < 2; ++s2)
#pragma unroll
      for (int nf = 0; nf < 2; ++nf) stA[s2][nf] = stB[s2][nf];
    b0 = b1;
  }

  // epilogue tile NT-1
  SOFTMAX(stA[0], m_r[0], l_r[0], oa0, 0);
  SOFTMAX(stA[1], m_r[1], l_r[1], oa1, 1);
  {
    short8 pa0 = *(const short8*)&Pl[w][0][g * 128 + lrow * 8];
    short8 pa1 = *(const short8*)&Pl[w][1][g * 128 + lrow * 8];
#pragma unroll
    for (int nf = 0; nf < 5; ++nf) {
      short8 bv = *(const short8*)&KV3[b0 + 3072 + g * 768 + (nf * 16 + lrow) * 8];
      oa0[nf] = __builtin_amdgcn_mfma_f32_16x16x32_bf16(bv, pa0, oa0[nf], 0, 0, 0);
      oa1[nf] = __builtin_amdgcn_mfma_f32_16x16x32_bf16(bv, pa1, oa1[nf], 0, 0, 0);
    }
  }

#pragma unroll
  for (int ss = 0; ss < 2; ++ss) {
    f32x4* oav = ss ? oa1 : oa0;
    float lt = l_r[ss];
    lt += __shfl_xor(lt, 16, 64);
    lt += __shfl_xor(lt, 32, 64);
    float rcp = 1.f / lt;
    size_t obase = (size_t)(q0 + ss * 16 + lrow) * HID + h * HD;
#pragma unroll
    for (int nf = 0; nf < 5; ++nf) {
      int d = nf * 16 + g * 4;
      if (d + 3 < HD) {
        uint2 pk = make_uint2(cvt_pk2(oav[nf][0] * rcp, oav[nf][1] * rcp),
                              cvt_pk2(oav[nf][2] * rcp, oav[nf][3] * rcp));
        *(uint2*)&o[obase + d] = pk;
      }
    }
  }
}

// ---------------- launch ----------------
extern "C" void kernel_launch(void* const* d_in, const int* in_sizes, int n_in,
                              void* d_out, int out_size, void* d_ws, size_t ws_size,
                              hipStream_t stream) {
  (void)in_sizes; (void)n_in; (void)out_size;
  const float* hidden = (const float*)d_in[0];
  const float* cosb = (const float*)d_in[1];
  const float* sinb = (const float*)d_in[2];
  const float* ln0g = (const float*)d_in[3];
  const float* ln0b = (const float*)d_in[4];
  const float* ln1g = (const float*)d_in[5];
  const float* ln1b = (const float*)d_in[6];
  const float* wqkv = (const float*)d_in[7];
  const float* bqkv = (const float*)d_in[8];
  const float* wo = (const float*)d_in[9];
  const float* bo = (const float*)d_in[10];
  const float* w0 = (const float*)d_in[11];
  const float* b0 = (const float*)d_in[12];
  const float* w1 = (const float*)d_in[13];
  const float* b1 = (const float*)d_in[14];

  char* p = (char*)d_ws;
  auto alloc = [&](size_t n) {
    char* r = p;
    p += (n + 255) & ~(size_t)255;
    return r;
  };
  bf16* wqkv_bf = (bf16*)alloc((size_t)3 * HID * HID * 2);
  bf16* wo_bf = (bf16*)alloc((size_t)HID * HID * 2);
  bf16* fc0_bf = (bf16*)alloc((size_t)MLPP * HID * 2);
  bf16* fc1_bf = (bf16*)alloc((size_t)HID * MLPP * 2);
  bf16* ln0_bf = (bf16*)alloc((size_t)SEQ * HID * 2);
  float* xqkv = (float*)alloc((size_t)SEQ * 3 * HID * 4);
  bf16* qp = (bf16*)alloc((size_t)NHEAD * SEQ * HDP * 2);
  bf16* kp = (bf16*)alloc((size_t)NHEAD * SEQ * HDP * 2);
  bf16* vt = (bf16*)alloc((size_t)NHEAD * HDP * SEQ * 2);
  bf16* attn_bf = (bf16*)alloc((size_t)SEQ * HID * 2);
  float* h1 = (float*)alloc((size_t)SEQ * HID * 4);
  bf16* ln1_bf = (bf16*)alloc((size_t)SEQ * HID * 2);
  bf16* gelu_bf = (bf16*)alloc((size_t)SEQ * MLPP * 2);
  if ((size_t)(p - (char*)d_ws) > ws_size) return;

  dim3 blk(256);
  cast_bf16_k<<<2048, blk, 0, stream>>>(wqkv, (unsigned*)wqkv_bf, 3 * HID * HID / 4);
  cast_bf16_k<<<1024, blk, 0, stream>>>(wo, (unsigned*)wo_bf, HID * HID / 4);
  cast_pad_rows_k<<<2048, blk, 0, stream>>>(w0, (unsigned*)fc0_bf, MLPD, HID / 4, MLPP * HID / 4);
  cast_pad_cols_k<<<2048, blk, 0, stream>>>(w1, (unsigned*)fc1_bf, MLPD / 4, MLPP / 4, HID * MLPP / 4);
  ln_k<<<SEQ, blk, 0, stream>>>(hidden, ln0g, ln0b, ln0_bf);
  gemm_bf16<0><<<dim3((3 * HID / 128) * (SEQ / 128)), blk, 0, stream>>>(
      ln0_bf, wqkv_bf, bqkv, 3 * HID, nullptr, xqkv, nullptr, SEQ, 3 * HID, HID);
  rope_split<<<dim3(SEQ / 64, NHEAD), blk, 0, stream>>>(xqkv, cosb, sinb, qp, kp, vt);
  flash_attn<<<dim3(768), dim3(128), 0, stream>>>(qp, kp, vt, attn_bf);
  gemm_bf16<1><<<dim3((HID / 128) * (SEQ / 128)), blk, 0, stream>>>(
      attn_bf, wo_bf, bo, HID, hidden, h1, nullptr, SEQ, HID, HID);
  ln_k<<<SEQ, blk, 0, stream>>>(h1, ln1g, ln1b, ln1_bf);
  gemm_bf16<2><<<dim3((MLPP / 128) * (SEQ / 128)), blk, 0, stream>>>(
      ln1_bf, fc0_bf, b0, MLPD, nullptr, nullptr, gelu_bf, SEQ, MLPP, HID);
  gemm_bf16<1><<<dim3((HID / 128) * (SEQ / 128)), blk, 0, stream>>>(
      gelu_bf, fc1_bf, b1, HID, h1, (float*)d_out, nullptr, SEQ, HID, MLPP);
}